// Round 10
// baseline (768.191 us; speedup 1.0000x reference)
//
#include <hip/hip_runtime.h>
#include <hip/hip_bf16.h>

typedef __attribute__((ext_vector_type(8))) short short8;
typedef __attribute__((ext_vector_type(4))) float f32x4;

#define GLOAD_LDS16(gp, lp)                                                      \
  __builtin_amdgcn_global_load_lds(                                              \
      (const __attribute__((address_space(1))) void*)(gp),                       \
      (__attribute__((address_space(3))) void*)(lp), 16, 0, 0)

#define SBAR() asm volatile("s_barrier" ::: "memory")
#define VMC(n)                                                                   \
  do {                                                                           \
    asm volatile("s_waitcnt vmcnt(" #n ")" ::: "memory");                        \
    __builtin_amdgcn_sched_barrier(0);                                           \
  } while (0)

__device__ __forceinline__ unsigned short f2bf_rne(float f) {
  union { float f; unsigned int u; } v; v.f = f;
  unsigned int u = v.u;
  u += 0x7fffu + ((u >> 16) & 1u);
  return (unsigned short)(u >> 16);
}

// ---------------------------------------------------------------- convert ----
__global__ void cvt_f32_bf16(const float* __restrict__ src,
                             unsigned short* __restrict__ dst, int n8) {
  int i = blockIdx.x * blockDim.x + threadIdx.x;
  int stride = gridDim.x * blockDim.x;
  const f32x4* s4 = (const f32x4*)src;
  short8* d8 = (short8*)dst;
  for (; i < n8; i += stride) {
    f32x4 a = s4[2 * i], b = s4[2 * i + 1];
    short8 o;
    o[0] = (short)f2bf_rne(a[0]); o[1] = (short)f2bf_rne(a[1]);
    o[2] = (short)f2bf_rne(a[2]); o[3] = (short)f2bf_rne(a[3]);
    o[4] = (short)f2bf_rne(b[0]); o[5] = (short)f2bf_rne(b[1]);
    o[6] = (short)f2bf_rne(b[2]); o[7] = (short)f2bf_rne(b[3]);
    d8[i] = o;
  }
}

// ------------------------------------------------- T = mask * 2 * (x @ A^T) ---
__global__ __launch_bounds__(256) void lora_t_kernel(
    const unsigned short* __restrict__ xb,
    const unsigned short* __restrict__ Ab,
    const int* __restrict__ offs,
    unsigned short* __restrict__ T)
{
  __shared__ unsigned short xs[64 * 64];
  __shared__ unsigned short as_[32 * 64];
  const int t = threadIdx.x;
  const int m0 = blockIdx.x * 64;
  const int l = t & 63, w = t >> 6;
  const int lr = l & 15, lk = (l >> 4) * 8;
  const int arow = t >> 3, acol = (t & 7) * 8;
  f32x4 acc0 = {0, 0, 0, 0}, acc1 = {0, 0, 0, 0};
  for (int kt = 0; kt < 64; ++kt) {
    __syncthreads();
    const int kof = kt * 64 + acol;
    GLOAD_LDS16(xb + (size_t)(m0 + arow) * 4096 + kof,      (char*)xs + (arow * 64 + acol) * 2);
    GLOAD_LDS16(xb + (size_t)(m0 + 32 + arow) * 4096 + kof, (char*)xs + ((32 + arow) * 64 + acol) * 2);
    GLOAD_LDS16(Ab + (size_t)arow * 4096 + kof,             (char*)as_ + (arow * 64 + acol) * 2);
    __syncthreads();
#pragma unroll
    for (int kk = 0; kk < 2; ++kk) {
      short8 a  = *(const short8*)&xs[(w * 16 + lr) * 64 + kk * 32 + lk];
      short8 b0 = *(const short8*)&as_[lr * 64 + kk * 32 + lk];
      short8 b1 = *(const short8*)&as_[(16 + lr) * 64 + kk * 32 + lk];
      acc0 = __builtin_amdgcn_mfma_f32_16x16x32_bf16(a, b0, acc0, 0, 0, 0);
      acc1 = __builtin_amdgcn_mfma_f32_16x16x32_bf16(a, b1, acc1, 0, 0, 0);
    }
  }
  const int rowb = (l >> 4) * 4;
#pragma unroll
  for (int j = 0; j < 4; ++j) {
    int m = m0 + w * 16 + rowb + j;
    int bb = m >> 12, s = m & 4095;
    int kcut = offs[bb]; if (kcut > 4096) kcut = 4096;
    bool keep = s >= 4096 - kcut;
    T[(size_t)m * 32 + lr]      = keep ? f2bf_rne(2.0f * acc0[j]) : (unsigned short)0;
    T[(size_t)m * 32 + 16 + lr] = keep ? f2bf_rne(2.0f * acc1[j]) : (unsigned short)0;
  }
}

// ------------------------------------------------------------- main GEMM -----
// NEW GEOMETRY for cross-block overlap: 128x128 tile, 256 threads (4 waves,
// 2x2), wave tile 64x64, BK=64, 2 LDS slots x 32 KB = 64 KiB -> TWO blocks
// co-resident per CU.  Blocks have independent barriers, so one block's LDS
// read/stage region overlaps the other's MFMA region (m114 mechanism) --
// the intra-block phase-lock that serialized R6-R8 no longer binds the CU.
// MFMA shape 16x16x32 + quarter-wave swizzle chunk^=(row&7): the ONLY
// combination measured conflict-free (R6: SQ_LDS_BANK_CONFLICT == 0).
// Per K-tile: P0 {read A4+B4 @kk0; stage ALL next tile (8 gloads); SBAR;
// 16 MFMA; SBAR}; P1 {read @kk1; SBAR; 16 MFMA; VMC(0); SBAR}.
__global__ __launch_bounds__(256, 2) void gemm_kernel(
    const unsigned short* __restrict__ xb,   // [16384][4096] bf16
    const unsigned short* __restrict__ Wb,   // [4096][4096]  bf16
    const unsigned short* __restrict__ Tm,   // [16384][32]   bf16 (mask+scale)
    const unsigned short* __restrict__ Bwb,  // [4096][32]    bf16
    const float* __restrict__ bias,          // [4096]
    float* __restrict__ out)                 // [16384][4096] f32
{
  constexpr int K = 4096;
  extern __shared__ char smem[];             // 64 KiB: 2 slots x (A 16K + B 16K)

  // bijective XCD swizzle (4096 blocks, %8==0)
  const int bid = blockIdx.x;
  const int swz = (bid & 7) * 512 + (bid >> 3);
  const int m0 = (swz >> 5) * 128;           // 128 M-tiles
  const int n0 = (swz & 31) * 128;           // 32 N-tiles

  const int t = threadIdx.x;
  const int l = t & 63, w = t >> 6;
  const int wr = w >> 1, wc = w & 1;         // 2x2 wave grid, wave tile 64x64
  const int lr = l & 15, hi = l >> 4;
  const int e0 = (hi ^ (lr & 7)) * 8;        // verified zero-conflict swizzle

  // staging: thread t -> 4 rounds q: LDS chunk q*256+t (row q*32+(t>>3),
  // cpos t&7); source chunk = cpos ^ (row&7) = (t&7)^((t>>3)&7) (q*32 = 0 mod 8)
  const int srow = t >> 3;
  const int schunk = ((t & 7) ^ ((t >> 3) & 7)) * 8;
  const unsigned short* pAg = xb + (size_t)(m0 + srow) * K + schunk;
  const unsigned short* pBg = Wb + (size_t)(n0 + srow) * K + schunk;
  unsigned short* sm = (unsigned short*)smem;
  const int ldst = t * 16;

#define STGA(SLOT, KT)                                                          \
  do {                                                                          \
    _Pragma("unroll")                                                           \
    for (int q_ = 0; q_ < 4; ++q_)                                              \
      GLOAD_LDS16(pAg + (size_t)q_ * 32 * K + (KT) * 64,                        \
                  smem + (SLOT) * 32768 + q_ * 4096 + ldst);                    \
  } while (0)
#define STGB(SLOT, KT)                                                          \
  do {                                                                          \
    _Pragma("unroll")                                                           \
    for (int q_ = 0; q_ < 4; ++q_)                                              \
      GLOAD_LDS16(pBg + (size_t)q_ * 32 * K + (KT) * 64,                        \
                  smem + (SLOT) * 32768 + 16384 + q_ * 4096 + ldst);            \
  } while (0)

  f32x4 acc[4][4];

  // --- LoRA prestep: register-direct (L2-resident), initializes acc ---
  {
    short8 la[4], lb[4];
#pragma unroll
    for (int i = 0; i < 4; ++i)
      la[i] = *(const short8*)(Tm + (size_t)(m0 + wr * 64 + i * 16 + lr) * 32 + hi * 8);
#pragma unroll
    for (int j = 0; j < 4; ++j)
      lb[j] = *(const short8*)(Bwb + (size_t)(n0 + wc * 64 + j * 16 + lr) * 32 + hi * 8);
#pragma unroll
    for (int i = 0; i < 4; ++i)
#pragma unroll
      for (int j = 0; j < 4; ++j)
        acc[i][j] = __builtin_amdgcn_mfma_f32_16x16x32_bf16(
            la[i], lb[j], (f32x4){0.f, 0.f, 0.f, 0.f}, 0, 0, 0);
  }

  // prologue: stage tile 0 into slot 0, drain, barrier
  STGA(0, 0); STGB(0, 0);
  VMC(0);
  SBAR();

#define PHASE(SLOT, KK, STG_STMT, WAIT_STMT)                                    \
  {                                                                             \
    const unsigned short* As = sm + (SLOT) * 16384;                             \
    const unsigned short* Bs = sm + (SLOT) * 16384 + 8192;                      \
    const int ek = e0 ^ ((KK) * 32);                                            \
    short8 af[4], bf[4];                                                        \
    _Pragma("unroll")                                                           \
    for (int i_ = 0; i_ < 4; ++i_)                                              \
      af[i_] = *(const short8*)(As + (wr * 64 + i_ * 16 + lr) * 64 + ek);       \
    _Pragma("unroll")                                                           \
    for (int j_ = 0; j_ < 4; ++j_)                                              \
      bf[j_] = *(const short8*)(Bs + (wc * 64 + j_ * 16 + lr) * 64 + ek);       \
    STG_STMT;                                                                   \
    SBAR();                                                                     \
    __builtin_amdgcn_s_setprio(1);                                              \
    _Pragma("unroll")                                                           \
    for (int i_ = 0; i_ < 4; ++i_)                                              \
      _Pragma("unroll")                                                         \
      for (int j_ = 0; j_ < 4; ++j_)                                            \
        acc[i_][j_] = __builtin_amdgcn_mfma_f32_16x16x32_bf16(                  \
            af[i_], bf[j_], acc[i_][j_], 0, 0, 0);                              \
    __builtin_amdgcn_s_setprio(0);                                              \
    WAIT_STMT;                                                                  \
    SBAR();                                                                     \
  }

  // Window t: P0 stages ALL of tile t+1 (8 gloads, in flight ~2 phases >= HBM
  // latency); P1 ends with VMC(0)+SBAR so tile t+1 is resident for window t+1.
  // The drain stall is masked by the co-resident sibling block.
  for (int I = 0; I < 31; ++I) {
    const int a = 2 * I;
    PHASE(0, 0, { STGA(1, a + 1); STGB(1, a + 1); }, ((void)0));
    PHASE(0, 1, ((void)0), VMC(0));
    PHASE(1, 0, { STGA(0, a + 2); STGB(0, a + 2); }, ((void)0));
    PHASE(1, 1, ((void)0), VMC(0));
  }
  // windows 62 (stage 63) and 63 (bare)
  PHASE(0, 0, { STGA(1, 63); STGB(1, 63); }, ((void)0));
  PHASE(0, 1, ((void)0), VMC(0));
  PHASE(1, 0, ((void)0), ((void)0));
  PHASE(1, 1, ((void)0), ((void)0));
#undef PHASE
#undef STGA
#undef STGB

  // epilogue: bias + store (C/D map: col = lr -> N, row = hi*4+e -> M)
  float bv[4];
#pragma unroll
  for (int j = 0; j < 4; ++j) bv[j] = bias[n0 + wc * 64 + j * 16 + lr];
  const int rowb = hi * 4;
#pragma unroll
  for (int i = 0; i < 4; ++i)
#pragma unroll
    for (int e = 0; e < 4; ++e) {
      int row = m0 + wr * 64 + i * 16 + rowb + e;
      float* orow = out + (size_t)row * 4096 + n0 + wc * 64;
#pragma unroll
      for (int j = 0; j < 4; ++j) orow[j * 16 + lr] = acc[i][j][e] + bv[j];
    }
}

// ----------------------------------------------------------------- launch ----
extern "C" void kernel_launch(void* const* d_in, const int* in_sizes, int n_in,
                              void* d_out, int out_size, void* d_ws, size_t ws_size,
                              hipStream_t stream) {
  const float* x   = (const float*)d_in[0];
  const int* offs  = (const int*)d_in[1];
  const float* W   = (const float*)d_in[2];
  const float* b   = (const float*)d_in[3];
  const float* A   = (const float*)d_in[4];
  const float* Bw  = (const float*)d_in[5];
  float* out = (float*)d_out;

  char* ws = (char*)d_ws;
  unsigned short* xb  = (unsigned short*)ws;
  unsigned short* Wb  = (unsigned short*)(ws + 134217728);
  unsigned short* Ab  = (unsigned short*)(ws + 167772160);
  unsigned short* Bwb = (unsigned short*)(ws + 168034304);
  unsigned short* T   = (unsigned short*)(ws + 168296448);

  hipFuncSetAttribute((const void*)gemm_kernel,
                      hipFuncAttributeMaxDynamicSharedMemorySize, 65536);

  cvt_f32_bf16<<<2048, 256, 0, stream>>>(x, xb, 67108864 / 8);
  cvt_f32_bf16<<<2048, 256, 0, stream>>>(W, Wb, 16777216 / 8);
  cvt_f32_bf16<<<64, 256, 0, stream>>>(A, Ab, 131072 / 8);
  cvt_f32_bf16<<<64, 256, 0, stream>>>(Bw, Bwb, 131072 / 8);
  lora_t_kernel<<<256, 256, 0, stream>>>(xb, Ab, offs, T);
  gemm_kernel<<<4096, 256, 65536, stream>>>(xb, Wb, T, Bwb, b, out);
}

// Round 11
// 608.158 us; speedup vs baseline: 1.2631x; 1.2631x over previous
//
#include <hip/hip_runtime.h>
#include <hip/hip_bf16.h>

typedef __attribute__((ext_vector_type(8))) short short8;
typedef __attribute__((ext_vector_type(4))) float f32x4;

#define GLOAD_LDS16(gp, lp)                                                      \
  __builtin_amdgcn_global_load_lds(                                              \
      (const __attribute__((address_space(1))) void*)(gp),                       \
      (__attribute__((address_space(3))) void*)(lp), 16, 0, 0)

#define SBAR() asm volatile("s_barrier" ::: "memory")
#define VMC(n)                                                                   \
  do {                                                                           \
    asm volatile("s_waitcnt vmcnt(" #n ")" ::: "memory");                        \
    __builtin_amdgcn_sched_barrier(0);                                           \
  } while (0)

__device__ __forceinline__ unsigned short f2bf_rne(float f) {
  union { float f; unsigned int u; } v; v.f = f;
  unsigned int u = v.u;
  u += 0x7fffu + ((u >> 16) & 1u);
  return (unsigned short)(u >> 16);
}

// ---------------------------------------------------------------- convert ----
__global__ void cvt_f32_bf16(const float* __restrict__ src,
                             unsigned short* __restrict__ dst, int n8) {
  int i = blockIdx.x * blockDim.x + threadIdx.x;
  int stride = gridDim.x * blockDim.x;
  const f32x4* s4 = (const f32x4*)src;
  short8* d8 = (short8*)dst;
  for (; i < n8; i += stride) {
    f32x4 a = s4[2 * i], b = s4[2 * i + 1];
    short8 o;
    o[0] = (short)f2bf_rne(a[0]); o[1] = (short)f2bf_rne(a[1]);
    o[2] = (short)f2bf_rne(a[2]); o[3] = (short)f2bf_rne(a[3]);
    o[4] = (short)f2bf_rne(b[0]); o[5] = (short)f2bf_rne(b[1]);
    o[6] = (short)f2bf_rne(b[2]); o[7] = (short)f2bf_rne(b[3]);
    d8[i] = o;
  }
}

// ------------------------------------------------- T = mask * 2 * (x @ A^T) ---
__global__ __launch_bounds__(256) void lora_t_kernel(
    const unsigned short* __restrict__ xb,
    const unsigned short* __restrict__ Ab,
    const int* __restrict__ offs,
    unsigned short* __restrict__ T)
{
  __shared__ unsigned short xs[64 * 64];
  __shared__ unsigned short as_[32 * 64];
  const int t = threadIdx.x;
  const int m0 = blockIdx.x * 64;
  const int l = t & 63, w = t >> 6;
  const int lr = l & 15, lk = (l >> 4) * 8;
  const int arow = t >> 3, acol = (t & 7) * 8;
  f32x4 acc0 = {0, 0, 0, 0}, acc1 = {0, 0, 0, 0};
  for (int kt = 0; kt < 64; ++kt) {
    __syncthreads();
    const int kof = kt * 64 + acol;
    GLOAD_LDS16(xb + (size_t)(m0 + arow) * 4096 + kof,      (char*)xs + (arow * 64 + acol) * 2);
    GLOAD_LDS16(xb + (size_t)(m0 + 32 + arow) * 4096 + kof, (char*)xs + ((32 + arow) * 64 + acol) * 2);
    GLOAD_LDS16(Ab + (size_t)arow * 4096 + kof,             (char*)as_ + (arow * 64 + acol) * 2);
    __syncthreads();
#pragma unroll
    for (int kk = 0; kk < 2; ++kk) {
      short8 a  = *(const short8*)&xs[(w * 16 + lr) * 64 + kk * 32 + lk];
      short8 b0 = *(const short8*)&as_[lr * 64 + kk * 32 + lk];
      short8 b1 = *(const short8*)&as_[(16 + lr) * 64 + kk * 32 + lk];
      acc0 = __builtin_amdgcn_mfma_f32_16x16x32_bf16(a, b0, acc0, 0, 0, 0);
      acc1 = __builtin_amdgcn_mfma_f32_16x16x32_bf16(a, b1, acc1, 0, 0, 0);
    }
  }
  const int rowb = (l >> 4) * 4;
#pragma unroll
  for (int j = 0; j < 4; ++j) {
    int m = m0 + w * 16 + rowb + j;
    int bb = m >> 12, s = m & 4095;
    int kcut = offs[bb]; if (kcut > 4096) kcut = 4096;
    bool keep = s >= 4096 - kcut;
    T[(size_t)m * 32 + lr]      = keep ? f2bf_rne(2.0f * acc0[j]) : (unsigned short)0;
    T[(size_t)m * 32 + 16 + lr] = keep ? f2bf_rne(2.0f * acc1[j]) : (unsigned short)0;
  }
}

// ------------------------------------------------------------- main GEMM -----
// R6 geometry (256x256 tile, BK=64, 2 slots, 8 waves, 16x16x32 MFMA,
// quarter-wave swizzle chunk^=(row&7) -- measured ZERO bank conflicts).
// NEW vs R6: m201-style wait discipline.  Stage order per tile rotated to
// [B1, A0, A1, B0] so a single VMC(2) at each tile boundary (end P3 / end P7)
// guarantees residency; no per-phase vmcnt / sched_barrier fences.
// Residency audit: at end-P7 VMC(2) leaves only s1.B0@t+3 (2 loads) in
// flight; slot0's B0(prev P3), B1(P4), A0(P5), A1(P6) are older -> landed.
// Symmetric at P3.  WAR audit: every stage target's last read is >=1 full
// barrier pair earlier (B1 read@kk1 in P7/P3-read-region -> staged next
// phase at earliest; A last read in P6/P2; B0 last read in P6/P2).
__global__ __launch_bounds__(512, 2) void gemm_kernel(
    const unsigned short* __restrict__ xb,   // [16384][4096] bf16
    const unsigned short* __restrict__ Wb,   // [4096][4096]  bf16
    const unsigned short* __restrict__ Tm,   // [16384][32]   bf16 (mask+scale)
    const unsigned short* __restrict__ Bwb,  // [4096][32]    bf16
    const float* __restrict__ bias,          // [4096]
    float* __restrict__ out)                 // [16384][4096] f32
{
  constexpr int K = 4096;
  extern __shared__ char smem[];             // 128 KiB

  const int bid = blockIdx.x;
  const int swz = (bid & 7) * 128 + (bid >> 3);
  const int m0 = (swz >> 4) * 256;
  const int n0 = (swz & 15) * 256;

  const int t = threadIdx.x;
  const int l = t & 63, w = t >> 6;
  const int wqr = w >> 2;
  const int pr = (w >> 1) & 1;
  const int pc = w & 1;
  const int lr = l & 15, hi = l >> 4;
  const int e0 = (hi ^ (lr & 7)) * 8;        // verified zero-conflict swizzle

  const int srow = t >> 3;
  const int schunk = ((t & 7) ^ ((t >> 3) & 7)) * 8;
  const unsigned short* pA0 = xb + (size_t)(m0 + srow) * K + schunk;
  const unsigned short* pA1 = xb + (size_t)(m0 + 128 + srow) * K + schunk;
  const unsigned short* pB0 = Wb + (size_t)(n0 + srow) * K + schunk;
  const unsigned short* pB1 = Wb + (size_t)(n0 + 128 + srow) * K + schunk;
  unsigned short* sm = (unsigned short*)smem;
  const int ldst = t * 16;

#define STG(PTR, SLOT, ISB, HALF, KT)                                           \
  do {                                                                          \
    const unsigned short* g_ = (PTR) + (KT) * 64;                               \
    char* d_ = smem + (SLOT) * 65536 + (ISB) * 32768 + (HALF) * 16384 + ldst;   \
    GLOAD_LDS16(g_, d_);                                                        \
    GLOAD_LDS16(g_ + (size_t)64 * K, d_ + 8192);                                \
  } while (0)

  f32x4 acc[2][4][4];
  short8 afr[4];   // persists across the qc1 phase (A reuse)

  // --- LoRA prestep: register-direct (L2-resident), initializes acc ---
  {
    const unsigned short* tp = Tm + (size_t)(m0 + wqr * 128 + pr * 64 + lr) * 32 + hi * 8;
    short8 la[4];
#pragma unroll
    for (int i = 0; i < 4; ++i) la[i] = *(const short8*)(tp + i * 512);
    short8 lb[2][4];
#pragma unroll
    for (int qc = 0; qc < 2; ++qc)
#pragma unroll
      for (int j = 0; j < 4; ++j)
        lb[qc][j] = *(const short8*)(Bwb + (size_t)(n0 + qc * 128 + pc * 64 + j * 16 + lr) * 32 + hi * 8);
#pragma unroll
    for (int qc = 0; qc < 2; ++qc)
#pragma unroll
      for (int i = 0; i < 4; ++i)
#pragma unroll
        for (int j = 0; j < 4; ++j)
          acc[qc][i][j] = __builtin_amdgcn_mfma_f32_16x16x32_bf16(
              la[i], lb[qc][j], (f32x4){0.f, 0.f, 0.f, 0.f}, 0, 0, 0);
  }

  // prologue: tile0 all 4 halves + s1.B0@1; VMC(2) leaves s1.B0 in flight.
  STG(pB1, 0, 1, 1, 0);
  STG(pA0, 0, 0, 0, 0);
  STG(pA1, 0, 0, 1, 0);
  STG(pB0, 0, 1, 0, 0);
  STG(pB0, 1, 1, 0, 1);
  VMC(2);
  SBAR();

  // READA phases load afr (A@kk) + bfr(B0); non-READA phases load bfr(B1) only.
#define PHASE(SLOT, QC, KK, READA, STG_STMT, WAIT_STMT)                         \
  {                                                                             \
    const unsigned short* Ah = sm + (SLOT) * 32768 + wqr * 8192;                \
    const unsigned short* Bh = sm + (SLOT) * 32768 + 16384 + (QC) * 8192;       \
    const int ek = e0 ^ ((KK) * 32);                                            \
    if (READA) {                                                                \
      _Pragma("unroll")                                                         \
      for (int i = 0; i < 4; ++i)                                               \
        afr[i] = *(const short8*)(Ah + (pr * 64 + i * 16 + lr) * 64 + ek);      \
    }                                                                           \
    short8 bfr[4];                                                              \
    _Pragma("unroll")                                                           \
    for (int j = 0; j < 4; ++j)                                                 \
      bfr[j] = *(const short8*)(Bh + (pc * 64 + j * 16 + lr) * 64 + ek);        \
    STG_STMT;                                                                   \
    SBAR();                                                                     \
    __builtin_amdgcn_s_setprio(1);                                              \
    _Pragma("unroll")                                                           \
    for (int i = 0; i < 4; ++i)                                                 \
      _Pragma("unroll")                                                         \
      for (int j = 0; j < 4; ++j)                                               \
        acc[QC][i][j] = __builtin_amdgcn_mfma_f32_16x16x32_bf16(                \
            afr[i], bfr[j], acc[QC][i][j], 0, 0, 0);                            \
    __builtin_amdgcn_s_setprio(0);                                              \
    WAIT_STMT;                                                                  \
    SBAR();                                                                     \
  }

  // stage stream (one half per phase): P0 s1.B1@a+1, P1 s1.A0, P2 s1.A1,
  // P3 s0.B0@a+2 +VMC(2); P4 s0.B1@a+2, P5 s0.A0, P6 s0.A1, P7 s1.B0@a+3
  // +VMC(2).  Only 2 waits per iteration.
  for (int I = 0; I < 31; ++I) {
    const int a = 2 * I;
    PHASE(0, 0, 0, 1, STG(pB1, 1, 1, 1, a + 1), ((void)0));
    PHASE(0, 1, 0, 0, STG(pA0, 1, 0, 0, a + 1), ((void)0));
    PHASE(0, 0, 1, 1, STG(pA1, 1, 0, 1, a + 1), ((void)0));
    PHASE(0, 1, 1, 0, STG(pB0, 0, 1, 0, a + 2), VMC(2));
    PHASE(1, 0, 0, 1, STG(pB1, 0, 1, 1, a + 2), ((void)0));
    PHASE(1, 1, 0, 0, STG(pA0, 0, 0, 0, a + 2), ((void)0));
    PHASE(1, 0, 1, 1, STG(pA1, 0, 0, 1, a + 2), ((void)0));
    PHASE(1, 1, 1, 0, STG(pB0, 1, 1, 0, a + 3), VMC(2));
  }
  // tail: slot0 = tile 62 (fully staged); stage tile 63's B1/A0/A1; drain.
  PHASE(0, 0, 0, 1, STG(pB1, 1, 1, 1, 63), ((void)0));
  PHASE(0, 1, 0, 0, STG(pA0, 1, 0, 0, 63), ((void)0));
  PHASE(0, 0, 1, 1, STG(pA1, 1, 0, 1, 63), ((void)0));
  PHASE(0, 1, 1, 0, ((void)0), VMC(0));
  PHASE(1, 0, 0, 1, ((void)0), ((void)0));
  PHASE(1, 1, 0, 0, ((void)0), ((void)0));
  PHASE(1, 0, 1, 1, ((void)0), ((void)0));
  PHASE(1, 1, 1, 0, ((void)0), ((void)0));
#undef PHASE
#undef STG

  // epilogue: bias + store (C/D map: col=lr -> N, row=hi*4+e -> M)
  float bv[2][4];
#pragma unroll
  for (int qc = 0; qc < 2; ++qc)
#pragma unroll
    for (int j = 0; j < 4; ++j)
      bv[qc][j] = bias[n0 + qc * 128 + pc * 64 + j * 16 + lr];
  const int rowb = hi * 4;
#pragma unroll
  for (int qc = 0; qc < 2; ++qc)
#pragma unroll
    for (int i = 0; i < 4; ++i)
#pragma unroll
      for (int e = 0; e < 4; ++e) {
        int row = m0 + wqr * 128 + pr * 64 + i * 16 + rowb + e;
        float* orow = out + (size_t)row * 4096 + n0 + qc * 128 + pc * 64;
#pragma unroll
        for (int j = 0; j < 4; ++j) orow[j * 16 + lr] = acc[qc][i][j][e] + bv[qc][j];
      }
}

// ----------------------------------------------------------------- launch ----
extern "C" void kernel_launch(void* const* d_in, const int* in_sizes, int n_in,
                              void* d_out, int out_size, void* d_ws, size_t ws_size,
                              hipStream_t stream) {
  const float* x   = (const float*)d_in[0];
  const int* offs  = (const int*)d_in[1];
  const float* W   = (const float*)d_in[2];
  const float* b   = (const float*)d_in[3];
  const float* A   = (const float*)d_in[4];
  const float* Bw  = (const float*)d_in[5];
  float* out = (float*)d_out;

  char* ws = (char*)d_ws;
  unsigned short* xb  = (unsigned short*)ws;
  unsigned short* Wb  = (unsigned short*)(ws + 134217728);
  unsigned short* Ab  = (unsigned short*)(ws + 167772160);
  unsigned short* Bwb = (unsigned short*)(ws + 168034304);
  unsigned short* T   = (unsigned short*)(ws + 168296448);

  hipFuncSetAttribute((const void*)gemm_kernel,
                      hipFuncAttributeMaxDynamicSharedMemorySize, 131072);

  cvt_f32_bf16<<<2048, 256, 0, stream>>>(x, xb, 67108864 / 8);
  cvt_f32_bf16<<<2048, 256, 0, stream>>>(W, Wb, 16777216 / 8);
  cvt_f32_bf16<<<64, 256, 0, stream>>>(A, Ab, 131072 / 8);
  cvt_f32_bf16<<<64, 256, 0, stream>>>(Bw, Bwb, 131072 / 8);
  lora_t_kernel<<<256, 256, 0, stream>>>(xb, Ab, offs, T);
  gemm_kernel<<<1024, 512, 131072, stream>>>(xb, Wb, T, Bwb, b, out);
}